// Round 3
// baseline (171.481 us; speedup 1.0000x reference)
//
#include <hip/hip_runtime.h>

// HoughCriterion: gaussian center-splat target + focal loss + scalar reduce.
// h0 [8,80,128,128], h1 [8,80,64,64], h2 [8,80,32,32] fp32;
// boxes [8,32,4] fp32 cxcywh normalized; labels [8,32] i32; image_sizes unused.
//
// Strategy: target!=0 covers only ~1.6% of pixels (box windows). Pass A streams
// ALL pixels with the pure-negative focal term (t=0, weight 1) — no box logic.
// Pass B (last 256 blocks of same grid) re-visits only box-window pixels and
// applies the exact correction (pos term, or (1-t)^4-1 neg reweight), using
// first-box-owns-pixel dedup for overlapping same-plane windows. negterm() is
// the identical instruction sequence in both passes so the correction is exact.
//
// ws float slots (all written unconditionally; no init needed):
//   [0,2560)     nl level0, slot = plane*4 + chunk
//   [2560,3200)  nl level1, slot = 2560 + plane
//   [3200,3840)  nl level2, slot = 3200 + plane
//   [3840,4096)  np per box   (box = b*32+n)
//   [4096,4352)  pl per box
//   [4352,4608)  nl-correction per box

#define BATCH 8
#define NBOX 32
#define NCH 80
#define NPLANE 640

__device__ __forceinline__ float sigclip(float h) {
    const float e = __expf(-h);
    const float p = __builtin_amdgcn_rcpf(1.0f + e);   // v_rcp_f32
    return fminf(fmaxf(p, 1e-4f), 1.0f - 1e-4f);
}
__device__ __forceinline__ float negterm(float h) {
    const float p = sigclip(h);
    return __logf(1.0f - p) * p * p;
}

__global__ __launch_bounds__(256) void hough_main_kernel(
    const float* __restrict__ h0, const float* __restrict__ h1,
    const float* __restrict__ h2,
    const float* __restrict__ boxes, const int* __restrict__ labels,
    float* __restrict__ ws)
{
    const int bid = blockIdx.x;
    const int tid = threadIdx.x;

    if (bid < 3840) {
        // ---------------- Pass A: uniform focal-neg streaming ----------------
        const float* hp; int nf4; int slot;
        if (bid < 2560) {            // level0: 4 chunks/plane; float off = bid*4096
            hp = h0 + ((size_t)bid << 12); nf4 = 1024; slot = bid;
        } else if (bid < 3200) {     // level1: 1 block/plane, 4096 px
            const int p = bid - 2560;
            hp = h1 + ((size_t)p << 12); nf4 = 1024; slot = 2560 + p;
        } else {                     // level2: 1 block/plane, 1024 px
            const int p = bid - 3200;
            hp = h2 + ((size_t)p << 10); nf4 = 256; slot = 3200 + p;
        }
        const float4* f4 = (const float4*)hp;
        float nl = 0.0f;
        for (int i = tid; i < nf4; i += 256) {
            const float4 q = f4[i];
            nl += negterm(q.x) + negterm(q.y) + negterm(q.z) + negterm(q.w);
        }
        for (int o = 32; o > 0; o >>= 1) nl += __shfl_down(nl, o, 64);
        __shared__ float sw[4];
        const int w = tid >> 6, l = tid & 63;
        if (l == 0) sw[w] = nl;
        __syncthreads();
        if (tid == 0) ws[slot] = sw[0] + sw[1] + sw[2] + sw[3];
        return;
    }

    // ---------------- Pass B: per-box window correction ----------------
    const int box = bid - 3840;
    const int b = box >> 5, n = box & 31;

    __shared__ float s_cx[NBOX], s_cy[NBOX], s_bw[NBOX], s_bh[NBOX];
    __shared__ int s_lab[NBOX];
    if (tid < NBOX) {
        const float* bp = boxes + (size_t)(b * NBOX + tid) * 4;
        s_cx[tid] = bp[0]; s_cy[tid] = bp[1];
        s_bw[tid] = bp[2]; s_bh[tid] = bp[3];
        s_lab[tid] = labels[b * NBOX + tid];
    }
    __syncthreads();

    const int c = s_lab[n];
    float np_ = 0.0f, pl_ = 0.0f, nld = 0.0f;
    const float* heats[3] = {h0, h1, h2};

    for (int lv = 0; lv < 3; ++lv) {
        const int lw = 7 - lv;
        const int W = 1 << lw;
        const float fW = (float)W;
        // own box params (reference FP order: bw=w*W, bh=h*W, (bw+bh)/4)
        const int xn = (int)floorf(s_cx[n] * fW);
        const int yn = (int)floorf(s_cy[n] * fW);
        int rn = (int)floorf((s_bw[n] * fW + s_bh[n] * fW) * 0.25f);
        rn = max(1, rn);
        const int wn = 2 * rn + 1;
        const int tot = wn * wn;
        const float* hb = heats[lv] + ((size_t)(b * NCH + c) << (2 * lw));

        for (int idx = tid; idx < tot; idx += 256) {
            const int dy = idx / wn;
            const int dx = idx - dy * wn;
            const int px = xn - rn + dx;
            const int py = yn - rn + dy;
            if (px < 0 || px >= W || py < 0 || py >= W) continue;

            bool owned = true;
            float t = 0.0f;
            for (int m = 0; m < NBOX; ++m) {
                if (s_lab[m] != c) continue;
                const int xm = (int)floorf(s_cx[m] * fW);
                const int ym = (int)floorf(s_cy[m] * fW);
                int rm = (int)floorf((s_bw[m] * fW + s_bh[m] * fW) * 0.25f);
                rm = max(1, rm);
                const int ddx = px - xm, ddy = py - ym;
                if (ddx < -rm || ddx > rm || ddy < -rm || ddy > rm) continue;
                if (m < n) { owned = false; break; }   // earlier box owns this px
                const float sig = (float)(2 * rm + 1) / 6.0f;
                const float i2 = 1.0f / (2.0f * sig * sig);
                t = fmaxf(t, __expf(-(float)(ddx * ddx + ddy * ddy) * i2));
            }
            if (!owned) continue;

            const float h = hb[py * W + px];
            const float n0 = negterm(h);          // what Pass A already added
            if (t == 1.0f) {                      // exact only at a box center
                const float p = sigclip(h);
                const float omp = 1.0f - p;
                pl_ += __logf(p) * omp * omp;
                np_ += 1.0f;
                nld -= n0;                        // remove the neg contribution
            } else {
                const float omt = 1.0f - t;
                const float nw4 = (omt * omt) * (omt * omt);
                nld += n0 * (nw4 - 1.0f);         // reweight correction
            }
        }
    }

    for (int o = 32; o > 0; o >>= 1) {
        np_ += __shfl_down(np_, o, 64);
        pl_ += __shfl_down(pl_, o, 64);
        nld += __shfl_down(nld, o, 64);
    }
    __shared__ float r_np[4], r_pl[4], r_nl[4];
    const int w = tid >> 6, l = tid & 63;
    if (l == 0) { r_np[w] = np_; r_pl[w] = pl_; r_nl[w] = nld; }
    __syncthreads();
    if (tid == 0) {
        ws[3840 + box] = r_np[0] + r_np[1] + r_np[2] + r_np[3];
        ws[4096 + box] = r_pl[0] + r_pl[1] + r_pl[2] + r_pl[3];
        ws[4352 + box] = r_nl[0] + r_nl[1] + r_nl[2] + r_nl[3];
    }
}

__global__ __launch_bounds__(256) void finalize_kernel(
    const float* __restrict__ ws, const int* __restrict__ labels,
    float* __restrict__ out)
{
    const int tid = threadIdx.x;
    float s = 0.0f;
    for (int p = tid; p < NPLANE; p += 256) {
        const int b = p / NCH, c = p - b * NCH;
        const float4 n4 = ((const float4*)ws)[p];       // level0 chunks 4p..4p+3
        float nl = n4.x + n4.y + n4.z + n4.w + ws[2560 + p] + ws[3200 + p];
        float np_ = 0.0f, pl_ = 0.0f;
        for (int m = 0; m < NBOX; ++m) {
            if (labels[b * NBOX + m] == c) {
                const int box = b * NBOX + m;
                np_ += ws[3840 + box];
                pl_ += ws[4096 + box];
                nl  += ws[4352 + box];
            }
        }
        const float loss = (np_ == 0.0f) ? (-nl) : (-(pl_ + nl) / np_);
        s += fminf(loss, 10.0f);
    }
    for (int o = 32; o > 0; o >>= 1) s += __shfl_down(s, o, 64);
    __shared__ float sw[4];
    const int w = tid >> 6, l = tid & 63;
    if (l == 0) sw[w] = s;
    __syncthreads();
    if (tid == 0) {
        const float mean = (sw[0] + sw[1] + sw[2] + sw[3]) * (1.0f / (float)NPLANE);
        const float lm = log1pf(mean);
        out[0] = lm / (1.0f + lm);
    }
}

extern "C" void kernel_launch(void* const* d_in, const int* in_sizes, int n_in,
                              void* d_out, int out_size, void* d_ws, size_t ws_size,
                              hipStream_t stream) {
    const float* h0 = (const float*)d_in[0];
    const float* h1 = (const float*)d_in[1];
    const float* h2 = (const float*)d_in[2];
    const float* boxes = (const float*)d_in[3];
    const int* labels = (const int*)d_in[4];
    // d_in[5] image_sizes: unused (cancels in reference math)

    float* ws = (float*)d_ws;   // 4608 floats, fully overwritten every call

    hough_main_kernel<<<4096, 256, 0, stream>>>(h0, h1, h2, boxes, labels, ws);
    finalize_kernel<<<1, 256, 0, stream>>>(ws, labels, (float*)d_out);
}

// Round 4
// 118.243 us; speedup vs baseline: 1.4502x; 1.4502x over previous
//
#include <hip/hip_runtime.h>

// HoughCriterion: gaussian center-splat target + focal loss + scalar reduce.
// h0 [8,80,128,128], h1 [8,80,64,64], h2 [8,80,32,32] fp32;
// boxes [8,32,4] fp32 cxcywh normalized; labels [8,32] i32; image_sizes unused.
//
// Pass B (bid<256, launched FIRST): per-box window correction with hoisted
//   box params + compacted same-class candidate list (avg len ~1.4).
// Pass A (bid in [256,896)): one block per (b,c) plane, pure focal-neg
//   streaming over all 3 levels (t=0, weight 1) — no box logic.
// negterm() is the identical instruction sequence in both passes so the
// Pass-B correction cancels Pass-A contributions exactly.
//
// ws float slots (all written unconditionally; no init needed):
//   [0,640)      nl per plane (Pass A)
//   [640,896)    np per box   (box = b*32+n)
//   [896,1152)   pl per box
//   [1152,1408)  nl-correction per box

#define BATCH 8
#define NBOX 32
#define NCH 80
#define NPLANE 640

__device__ __forceinline__ float sigclip(float h) {
    const float e = __expf(-h);
    const float p = __builtin_amdgcn_rcpf(1.0f + e);   // v_rcp_f32
    return fminf(fmaxf(p, 1e-4f), 1.0f - 1e-4f);
}
__device__ __forceinline__ float negterm(float h) {
    const float p = sigclip(h);
    return __logf(1.0f - p) * p * p;
}

__global__ __launch_bounds__(256) void hough_main_kernel(
    const float* __restrict__ h0, const float* __restrict__ h1,
    const float* __restrict__ h2,
    const float* __restrict__ boxes, const int* __restrict__ labels,
    float* __restrict__ ws)
{
    const int bid = blockIdx.x;
    const int tid = threadIdx.x;

    if (bid >= 256) {
        // ---------------- Pass A: per-plane focal-neg streaming ----------------
        const int p = bid - 256;                 // plane = b*NCH + c
        float nl = 0.0f;
        {   // level 0: 16384 px
            const float4* f4 = (const float4*)(h0 + ((size_t)p << 14));
            for (int i = tid; i < 4096; i += 256) {
                const float4 q = f4[i];
                nl += negterm(q.x) + negterm(q.y) + negterm(q.z) + negterm(q.w);
            }
        }
        {   // level 1: 4096 px
            const float4* f4 = (const float4*)(h1 + ((size_t)p << 12));
            for (int i = tid; i < 1024; i += 256) {
                const float4 q = f4[i];
                nl += negterm(q.x) + negterm(q.y) + negterm(q.z) + negterm(q.w);
            }
        }
        {   // level 2: 1024 px
            const float4* f4 = (const float4*)(h2 + ((size_t)p << 10));
            for (int i = tid; i < 256; i += 256) {
                const float4 q = f4[i];
                nl += negterm(q.x) + negterm(q.y) + negterm(q.z) + negterm(q.w);
            }
        }
        for (int o = 32; o > 0; o >>= 1) nl += __shfl_down(nl, o, 64);
        __shared__ float sw[4];
        const int w = tid >> 6, l = tid & 63;
        if (l == 0) sw[w] = nl;
        __syncthreads();
        if (tid == 0) ws[p] = sw[0] + sw[1] + sw[2] + sw[3];
        return;
    }

    // ---------------- Pass B: per-box window correction ----------------
    const int box = bid;
    const int b = box >> 5, n = box & 31;

    __shared__ int   s_lab[NBOX];
    __shared__ int   s_xm[3][NBOX], s_ym[3][NBOX], s_rm[3][NBOX];
    __shared__ float s_i2[3][NBOX];
    __shared__ int   s_cand[NBOX];
    __shared__ int   s_kc;
    if (tid < NBOX) s_lab[tid] = labels[b * NBOX + tid];
    if (tid < 3 * NBOX) {
        const int lv = tid >> 5, m = tid & 31;
        const float fW = (float)(1 << (7 - lv));
        const float* bp = boxes + (size_t)(b * NBOX + m) * 4;
        s_xm[lv][m] = (int)floorf(bp[0] * fW);
        s_ym[lv][m] = (int)floorf(bp[1] * fW);
        int r = (int)floorf((bp[2] * fW + bp[3] * fW) * 0.25f);
        r = max(1, r);
        s_rm[lv][m] = r;
        const float sig = (float)(2 * r + 1) / 6.0f;
        s_i2[lv][m] = 1.0f / (2.0f * sig * sig);
    }
    __syncthreads();
    const int c = s_lab[n];
    if (tid == 0) {
        int kc = 0;
        for (int m = 0; m < NBOX; ++m)
            if (s_lab[m] == c) s_cand[kc++] = m;   // ascending order
        s_kc = kc;
    }
    __syncthreads();
    const int kc = s_kc;

    float np_ = 0.0f, pl_ = 0.0f, nld = 0.0f;
    const float* heats[3] = {h0, h1, h2};

    for (int lv = 0; lv < 3; ++lv) {
        const int lw = 7 - lv;
        const int W = 1 << lw;
        const int xn = s_xm[lv][n], yn = s_ym[lv][n], rn = s_rm[lv][n];
        const int wn = 2 * rn + 1;
        const int tot = wn * wn;
        const float inv_wn = __builtin_amdgcn_rcpf((float)wn);
        const float* hb = heats[lv] + ((size_t)(b * NCH + c) << (2 * lw));

        for (int idx = tid; idx < tot; idx += 256) {
            int dy = (int)((float)idx * inv_wn);
            int rem = idx - dy * wn;
            if (rem < 0)        { dy -= 1; rem += wn; }
            else if (rem >= wn) { dy += 1; rem -= wn; }
            const int px = xn - rn + rem;
            const int py = yn - rn + dy;
            if (px < 0 || px >= W || py < 0 || py >= W) continue;

            bool owned = true;
            float t = 0.0f;
            for (int j = 0; j < kc; ++j) {
                const int m = s_cand[j];
                const int rm = s_rm[lv][m];
                const int ddx = px - s_xm[lv][m], ddy = py - s_ym[lv][m];
                if (ddx < -rm || ddx > rm || ddy < -rm || ddy > rm) continue;
                if (m < n) { owned = false; break; }   // earlier box owns px
                t = fmaxf(t, __expf(-(float)(ddx * ddx + ddy * ddy) * s_i2[lv][m]));
            }
            if (!owned) continue;

            const float h = hb[py * W + px];
            const float n0 = negterm(h);          // what Pass A already added
            if (t == 1.0f) {                      // exact only at a box center
                const float p = sigclip(h);
                const float omp = 1.0f - p;
                pl_ += __logf(p) * omp * omp;
                np_ += 1.0f;
                nld -= n0;                        // remove neg contribution
            } else {
                const float omt = 1.0f - t;
                const float nw4 = (omt * omt) * (omt * omt);
                nld += n0 * (nw4 - 1.0f);         // reweight correction
            }
        }
    }

    for (int o = 32; o > 0; o >>= 1) {
        np_ += __shfl_down(np_, o, 64);
        pl_ += __shfl_down(pl_, o, 64);
        nld += __shfl_down(nld, o, 64);
    }
    __shared__ float r_np[4], r_pl[4], r_nl[4];
    const int w = tid >> 6, l = tid & 63;
    if (l == 0) { r_np[w] = np_; r_pl[w] = pl_; r_nl[w] = nld; }
    __syncthreads();
    if (tid == 0) {
        ws[640 + box]  = r_np[0] + r_np[1] + r_np[2] + r_np[3];
        ws[896 + box]  = r_pl[0] + r_pl[1] + r_pl[2] + r_pl[3];
        ws[1152 + box] = r_nl[0] + r_nl[1] + r_nl[2] + r_nl[3];
    }
}

__global__ __launch_bounds__(256) void finalize_kernel(
    const float* __restrict__ ws, const int* __restrict__ labels,
    float* __restrict__ out)
{
    const int tid = threadIdx.x;
    float s = 0.0f;
    for (int p = tid; p < NPLANE; p += 256) {
        const int b = p / NCH, c = p - b * NCH;
        float nl = ws[p];
        float np_ = 0.0f, pl_ = 0.0f;
        for (int m = 0; m < NBOX; ++m) {
            if (labels[b * NBOX + m] == c) {
                const int box = b * NBOX + m;
                np_ += ws[640 + box];
                pl_ += ws[896 + box];
                nl  += ws[1152 + box];
            }
        }
        const float loss = (np_ == 0.0f) ? (-nl) : (-(pl_ + nl) / np_);
        s += fminf(loss, 10.0f);
    }
    for (int o = 32; o > 0; o >>= 1) s += __shfl_down(s, o, 64);
    __shared__ float sw[4];
    const int w = tid >> 6, l = tid & 63;
    if (l == 0) sw[w] = s;
    __syncthreads();
    if (tid == 0) {
        const float mean = (sw[0] + sw[1] + sw[2] + sw[3]) * (1.0f / (float)NPLANE);
        const float lm = log1pf(mean);
        out[0] = lm / (1.0f + lm);
    }
}

extern "C" void kernel_launch(void* const* d_in, const int* in_sizes, int n_in,
                              void* d_out, int out_size, void* d_ws, size_t ws_size,
                              hipStream_t stream) {
    const float* h0 = (const float*)d_in[0];
    const float* h1 = (const float*)d_in[1];
    const float* h2 = (const float*)d_in[2];
    const float* boxes = (const float*)d_in[3];
    const int* labels = (const int*)d_in[4];
    // d_in[5] image_sizes: unused (cancels in reference math)

    float* ws = (float*)d_ws;   // 1408 floats, fully overwritten every call

    hough_main_kernel<<<896, 256, 0, stream>>>(h0, h1, h2, boxes, labels, ws);
    finalize_kernel<<<1, 256, 0, stream>>>(ws, labels, (float*)d_out);
}

// Round 5
// 114.989 us; speedup vs baseline: 1.4913x; 1.0283x over previous
//
#include <hip/hip_runtime.h>

// HoughCriterion: gaussian center-splat target + focal loss + scalar reduce.
// h0 [8,80,128,128], h1 [8,80,64,64], h2 [8,80,32,32] fp32;
// boxes [8,32,4] fp32 cxcywh normalized; labels [8,32] i32; image_sizes unused.
//
// Pass B (bid<768, dispatched FIRST): one block per (level, box) window
//   correction; hoisted box params + compacted same-class candidate list.
// Pass A (bid in [768,4608)): R2-granularity pure focal-neg streaming,
//   3840 light blocks (level0: 4 chunks/plane; level1/2: 1 block/plane).
// negterm() is the identical instruction sequence in both passes so the
// Pass-B correction cancels Pass-A contributions exactly.
//
// ws float slots (all written unconditionally; no init needed):
//   [0,3840)     nl Pass-A partial per block (level0: plane*4+chunk;
//                2560+plane level1; 3200+plane level2)
//   [3840,4608)  np per (lv,box)  slot = 3840 + lv*256 + box
//   [4608,5376)  pl per (lv,box)
//   [5376,6144)  nl-correction per (lv,box)

#define BATCH 8
#define NBOX 32
#define NCH 80
#define NPLANE 640
#define NB_B 768          // 3 levels * 256 boxes
#define GRID (NB_B + 3840)

__device__ __forceinline__ float sigclip(float h) {
    const float e = __expf(-h);
    const float p = __builtin_amdgcn_rcpf(1.0f + e);   // v_rcp_f32
    return fminf(fmaxf(p, 1e-4f), 1.0f - 1e-4f);
}
__device__ __forceinline__ float negterm(float h) {
    const float p = sigclip(h);
    return __logf(1.0f - p) * p * p;
}

__global__ __launch_bounds__(256) void hough_main_kernel(
    const float* __restrict__ h0, const float* __restrict__ h1,
    const float* __restrict__ h2,
    const float* __restrict__ boxes, const int* __restrict__ labels,
    float* __restrict__ ws)
{
    const int bid = blockIdx.x;
    const int tid = threadIdx.x;

    if (bid >= NB_B) {
        // ------------- Pass A: fine-grained focal-neg streaming -------------
        const int aid = bid - NB_B;
        const float* hp; int nf4;
        if (aid < 2560) {            // level0: plane=aid>>2, chunk=aid&3
            hp = h0 + ((size_t)aid << 12); nf4 = 1024;
        } else if (aid < 3200) {     // level1
            hp = h1 + ((size_t)(aid - 2560) << 12); nf4 = 1024;
        } else {                     // level2
            hp = h2 + ((size_t)(aid - 3200) << 10); nf4 = 256;
        }
        const float4* f4 = (const float4*)hp;
        float nl = 0.0f;
        for (int i = tid; i < nf4; i += 256) {
            const float4 q = f4[i];
            nl += negterm(q.x) + negterm(q.y) + negterm(q.z) + negterm(q.w);
        }
        for (int o = 32; o > 0; o >>= 1) nl += __shfl_down(nl, o, 64);
        __shared__ float sw[4];
        const int w = tid >> 6, l = tid & 63;
        if (l == 0) sw[w] = nl;
        __syncthreads();
        if (tid == 0) ws[aid] = sw[0] + sw[1] + sw[2] + sw[3];
        return;
    }

    // ------------- Pass B: per-(level,box) window correction -------------
    const int lv = bid >> 8;          // 0,1,2
    const int box = bid & 255;
    const int b = box >> 5, n = box & 31;
    const int lw = 7 - lv;
    const int W = 1 << lw;
    const float fW = (float)W;

    __shared__ int   s_lab[NBOX];
    __shared__ int   s_xm[NBOX], s_ym[NBOX], s_rm[NBOX];
    __shared__ float s_i2[NBOX];
    __shared__ int   s_cand[NBOX];
    __shared__ int   s_kc;
    if (tid < NBOX) {
        s_lab[tid] = labels[b * NBOX + tid];
        const float* bp = boxes + (size_t)(b * NBOX + tid) * 4;
        s_xm[tid] = (int)floorf(bp[0] * fW);
        s_ym[tid] = (int)floorf(bp[1] * fW);
        int r = (int)floorf((bp[2] * fW + bp[3] * fW) * 0.25f);
        r = max(1, r);
        s_rm[tid] = r;
        const float sig = (float)(2 * r + 1) / 6.0f;
        s_i2[tid] = 1.0f / (2.0f * sig * sig);
    }
    __syncthreads();
    const int c = s_lab[n];
    if (tid == 0) {
        int kc = 0;
        for (int m = 0; m < NBOX; ++m)
            if (s_lab[m] == c) s_cand[kc++] = m;   // ascending
        s_kc = kc;
    }
    __syncthreads();
    const int kc = s_kc;

    const int xn = s_xm[n], yn = s_ym[n], rn = s_rm[n];
    const int wn = 2 * rn + 1;
    const int tot = wn * wn;
    const float inv_wn = __builtin_amdgcn_rcpf((float)wn);
    const float* hb = ((lv == 0) ? h0 : (lv == 1) ? h1 : h2)
                      + ((size_t)(b * NCH + c) << (2 * lw));

    float np_ = 0.0f, pl_ = 0.0f, nld = 0.0f;
    for (int idx = tid; idx < tot; idx += 256) {
        int dy = (int)((float)idx * inv_wn);
        int rem = idx - dy * wn;
        if (rem < 0)        { dy -= 1; rem += wn; }
        else if (rem >= wn) { dy += 1; rem -= wn; }
        const int px = xn - rn + rem;
        const int py = yn - rn + dy;
        if (px < 0 || px >= W || py < 0 || py >= W) continue;

        bool owned = true;
        float t = 0.0f;
        for (int j = 0; j < kc; ++j) {
            const int m = s_cand[j];
            const int rm = s_rm[m];
            const int ddx = px - s_xm[m], ddy = py - s_ym[m];
            if (ddx < -rm || ddx > rm || ddy < -rm || ddy > rm) continue;
            if (m < n) { owned = false; break; }   // earlier box owns px
            t = fmaxf(t, __expf(-(float)(ddx * ddx + ddy * ddy) * s_i2[m]));
        }
        if (!owned) continue;

        const float h = hb[py * W + px];
        const float n0 = negterm(h);          // what Pass A already added
        if (t == 1.0f) {                      // exact only at a box center
            const float p = sigclip(h);
            const float omp = 1.0f - p;
            pl_ += __logf(p) * omp * omp;
            np_ += 1.0f;
            nld -= n0;                        // remove neg contribution
        } else {
            const float omt = 1.0f - t;
            const float nw4 = (omt * omt) * (omt * omt);
            nld += n0 * (nw4 - 1.0f);         // reweight correction
        }
    }

    for (int o = 32; o > 0; o >>= 1) {
        np_ += __shfl_down(np_, o, 64);
        pl_ += __shfl_down(pl_, o, 64);
        nld += __shfl_down(nld, o, 64);
    }
    __shared__ float r_np[4], r_pl[4], r_nl[4];
    const int w = tid >> 6, l = tid & 63;
    if (l == 0) { r_np[w] = np_; r_pl[w] = pl_; r_nl[w] = nld; }
    __syncthreads();
    if (tid == 0) {
        const int slot = lv * 256 + box;
        ws[3840 + slot] = r_np[0] + r_np[1] + r_np[2] + r_np[3];
        ws[4608 + slot] = r_pl[0] + r_pl[1] + r_pl[2] + r_pl[3];
        ws[5376 + slot] = r_nl[0] + r_nl[1] + r_nl[2] + r_nl[3];
    }
}

__global__ __launch_bounds__(256) void finalize_kernel(
    const float* __restrict__ ws, const int* __restrict__ labels,
    float* __restrict__ out)
{
    const int tid = threadIdx.x;
    float s = 0.0f;
    for (int p = tid; p < NPLANE; p += 256) {
        const int b = p / NCH, c = p - b * NCH;
        const float4 n4 = ((const float4*)ws)[p];       // level0 chunks
        float nl = n4.x + n4.y + n4.z + n4.w + ws[2560 + p] + ws[3200 + p];
        float np_ = 0.0f, pl_ = 0.0f;
        for (int m = 0; m < NBOX; ++m) {
            if (labels[b * NBOX + m] == c) {
                const int box = b * NBOX + m;
                #pragma unroll
                for (int lv = 0; lv < 3; ++lv) {
                    const int slot = lv * 256 + box;
                    np_ += ws[3840 + slot];
                    pl_ += ws[4608 + slot];
                    nl  += ws[5376 + slot];
                }
            }
        }
        const float loss = (np_ == 0.0f) ? (-nl) : (-(pl_ + nl) / np_);
        s += fminf(loss, 10.0f);
    }
    for (int o = 32; o > 0; o >>= 1) s += __shfl_down(s, o, 64);
    __shared__ float sw[4];
    const int w = tid >> 6, l = tid & 63;
    if (l == 0) sw[w] = s;
    __syncthreads();
    if (tid == 0) {
        const float mean = (sw[0] + sw[1] + sw[2] + sw[3]) * (1.0f / (float)NPLANE);
        const float lm = log1pf(mean);
        out[0] = lm / (1.0f + lm);
    }
}

extern "C" void kernel_launch(void* const* d_in, const int* in_sizes, int n_in,
                              void* d_out, int out_size, void* d_ws, size_t ws_size,
                              hipStream_t stream) {
    const float* h0 = (const float*)d_in[0];
    const float* h1 = (const float*)d_in[1];
    const float* h2 = (const float*)d_in[2];
    const float* boxes = (const float*)d_in[3];
    const int* labels = (const int*)d_in[4];
    // d_in[5] image_sizes: unused (cancels in reference math)

    float* ws = (float*)d_ws;   // 6144 floats, fully overwritten every call

    hough_main_kernel<<<GRID, 256, 0, stream>>>(h0, h1, h2, boxes, labels, ws);
    finalize_kernel<<<1, 256, 0, stream>>>(ws, labels, (float*)d_out);
}